// Round 12
// baseline (224.924 us; speedup 1.0000x reference)
//
#include <hip/hip_runtime.h>
#include <math.h>

#define Bsz 1024
#define Din 512
#define Hdim 1024
#define Aact 64
#define MAXT 23   // max row-tiles across experts: 7 partial + 16
#define NXCD 8

// out layout (float32): option_probs[1024*8] | action_probs[1024*64] | term[1024] | opt_argmax[1024] | sel_action[1024]
#define OFF_ACT   8192
#define OFF_TERM  73728
#define OFF_OARG  74752
#define OFF_SACT  75776

// ---------------- threefry2x32-20, key (0,42), partitionable XOR-fold (verified R3-R11) ----------------
__device__ __forceinline__ unsigned rotl32(unsigned x, int d){ return (x << d) | (x >> (32 - d)); }

__device__ __forceinline__ void threefry_042(unsigned& x0, unsigned& x1){
  const unsigned ks0 = 0u, ks1 = 42u, ks2 = 0x1BD11BDAu ^ 0u ^ 42u;
  x0 += ks0; x1 += ks1;
#define TFR(r) { x0 += x1; x1 = rotl32(x1, r); x1 ^= x0; }
  TFR(13) TFR(15) TFR(26) TFR(6)  x0 += ks1; x1 += ks2 + 1u;
  TFR(17) TFR(29) TFR(16) TFR(24) x0 += ks2; x1 += ks0 + 2u;
  TFR(13) TFR(15) TFR(26) TFR(6)  x0 += ks0; x1 += ks1 + 3u;
  TFR(17) TFR(29) TFR(16) TFR(24) x0 += ks1; x1 += ks2 + 4u;
  TFR(13) TFR(15) TFR(26) TFR(6)  x0 += ks2; x1 += ks0 + 5u;
#undef TFR
}

__device__ __forceinline__ float gumbel_at(int idx){
  unsigned x0 = 0u, x1 = (unsigned)idx;
  threefry_042(x0, x1);
  unsigned bits = x0 ^ x1;
  float f = __uint_as_float((bits >> 9) | 0x3F800000u) - 1.0f;
  float u = fmaxf(f, 1.1754944e-38f);
  return -logf(-logf(u));
}

// ---------------- 64x64 tile GEMM, 8 independent waves = split-K x8, 8x8/thread ----------------
// R12: TRUE double-buffered per-wave staging, NO manual lgkmcnt in K-loop.
// Rationale: R5/R8/R10/R11 all pinned at 76-85us, VALUBusy 21-24% regardless of spills/traffic
// -> latency serialization from single-buffer waits (store->wait->compute->wait). With dbuf,
// stores target buf[p^1] while compute reads buf[p]; cross-iteration RAW separated by a full
// compute phase + compiler's in-order counted lgkmcnt on read-uses (DS completes in order/wave).
// LDS exactly 64KB (8 waves x 2 bufs x 4KB) -> 2 blocks/CU; reduce overlays dead staging.
template<bool GATHER, bool DENSE>
__global__ __launch_bounds__(512)
void gemm_splitk8(const float* __restrict__ A, int lda,
                  const float* __restrict__ W0, const float* __restrict__ W1,
                  long long wstride,
                  const float* __restrict__ b0, const float* __restrict__ b1,
                  int bstride,
                  float* __restrict__ C0, float* __restrict__ C1,
                  int N, int K,
                  const int* __restrict__ order, const int* __restrict__ offsets,
                  const int* __restrict__ tlist)
{
  const float* W; const float* bias; float* C;
  int mbase, r1, n0;
  if (DENSE){
    const int bid = (int)(blockIdx.x + gridDim.x * (blockIdx.y + gridDim.y * blockIdx.z)); // 0..511
    const int wf = (bid % NXCD) * (512 / NXCD) + bid / NXCD;   // bijective XCD swizzle (512%8==0)
    const int ny = wf & 15, mx = (wf >> 4) & 15, z = wf >> 8;
    mbase = mx * 64; r1 = Bsz; n0 = ny * 64;
    W = z ? W1 : W0; bias = z ? b1 : b0; C = z ? C1 : C0;
  } else {
    const int bid = (int)(blockIdx.x + gridDim.x * blockIdx.y); // 368 = 46*8, bijective
    const int wf = (bid % NXCD) * ((MAXT * 16) / NXCD) + bid / NXCD;
    const int i = wf >> 4;
    if (i >= tlist[0]) return;
    const int o = tlist[1 + 2*i];
    mbase = tlist[2 + 2*i];
    r1 = offsets[o + 1];
    n0 = (wf & 15) * 64;
    W = W0 + (long long)o * wstride; bias = b0 + o * bstride; C = C0;
  }

  __shared__ float lds[16384];   // 64KB: 8 waves x [buf0 1024 | buf1 1024]; reduce overlays after K-loop

  const int tid = threadIdx.x;
  const int wv = tid >> 6, lane = tid & 63;
  const int ty = lane >> 3, tx = lane & 7;
  const int KC = K >> 3, NT = KC >> 3;      // per-wave K chunk; 8-k sub-tiles
  const int k0 = wv * KC;
  const int bkr = lane >> 4;                // B: base k-row (0..3)
  const int bnc = (lane & 15) * 4;          // B: column quad

  int grow = mbase + lane;
  int arow = grow < r1 ? grow : mbase;
  if (GATHER) arow = order[arow];
  const float* Ap = A + (long long)arow * lda + k0;
  const float* Wp = W + (long long)k0 * N + n0 + bnc;

  float* myst = lds + wv * 2048;            // [buf p: As 8x64 | Bs 8x64] x 2

  float acc[8][8];
#pragma unroll
  for (int i = 0; i < 8; i++)
#pragma unroll
    for (int j = 0; j < 8; j++) acc[i][j] = 0.f;

  float4 a4[2], b4[2];

#define LOADT(it) {                                                          \
    const float* ap = Ap + (it) * 8;                                         \
    a4[0] = *(const float4*)(ap + 0);  a4[1] = *(const float4*)(ap + 4);     \
    const float* wp = Wp + (long long)((it) * 8 + bkr) * N;                  \
    b4[0] = *(const float4*)(wp);                                            \
    b4[1] = *(const float4*)(wp + (long long)4 * N); }

#define STORET(p) {                                                          \
    float* As = myst + (p) * 1024;                                           \
    float* Bs = As + 512;                                                    \
    _Pragma("unroll")                                                        \
    for (int q = 0; q < 2; q++){                                             \
      As[(q*4 + 0)*64 + lane] = a4[q].x;                                     \
      As[(q*4 + 1)*64 + lane] = a4[q].y;                                     \
      As[(q*4 + 2)*64 + lane] = a4[q].z;                                     \
      As[(q*4 + 3)*64 + lane] = a4[q].w; }                                   \
    _Pragma("unroll")                                                        \
    for (int r = 0; r < 2; r++)                                              \
      *(float4*)(Bs + (bkr + r*4)*64 + bnc) = b4[r]; }

  LOADT(0); STORET(0); LOADT(1);

  int p = 0;
  for (int it = 0; it < NT; ++it){
    if (it + 1 < NT){
      STORET(p ^ 1);                        // vmcnt wait (internal) for LOADT(it+1); writes other buf
      if (it + 2 < NT) LOADT(it + 2);       // issue next global loads early
    }
    const float* As = myst + p * 1024;      // reads of buf p: stores landed >=1 compute-phase ago;
    const float* Bs = As + 512;             // compiler's counted lgkmcnt on read-uses covers hazards
#pragma unroll
    for (int kk = 0; kk < 8; ++kk){
      float4 av0 = *(const float4*)(As + kk*64 + ty*8);
      float4 av1 = *(const float4*)(As + kk*64 + ty*8 + 4);
      float4 bv0 = *(const float4*)(Bs + kk*64 + tx*8);
      float4 bv1 = *(const float4*)(Bs + kk*64 + tx*8 + 4);
      float a[8] = {av0.x,av0.y,av0.z,av0.w,av1.x,av1.y,av1.z,av1.w};
      float b[8] = {bv0.x,bv0.y,bv0.z,bv0.w,bv1.x,bv1.y,bv1.z,bv1.w};
#pragma unroll
      for (int i = 0; i < 8; i++)
#pragma unroll
        for (int j = 0; j < 8; j++) acc[i][j] = fmaf(a[i], b[j], acc[i][j]);
    }
    p ^= 1;
  }
#undef LOADT
#undef STORET

  // ---- log-tree cross-wave reduce in HALF-acc rounds (regions overlay dead staging) ----
  // region r: 64 lanes x 33 floats (stride 33 -> bank = lane, conflict-free). 4 regions = 33.8KB < 64KB.
#define RW(r, h) { float* q = lds + (r) * 2112 + lane * 33;                  \
    _Pragma("unroll")                                                        \
    for (int i = 0; i < 4; i++)                                              \
      _Pragma("unroll")                                                      \
      for (int j = 0; j < 8; j++) q[i*8 + j] = acc[(h)*4 + i][j]; }
#define RA(r, h) { const float* q = lds + (r) * 2112 + lane * 33;            \
    _Pragma("unroll")                                                        \
    for (int i = 0; i < 4; i++)                                              \
      _Pragma("unroll")                                                      \
      for (int j = 0; j < 8; j++) acc[(h)*4 + i][j] += q[i*8 + j]; }

#pragma unroll
  for (int h = 0; h < 2; ++h){
    __syncthreads();
    if (wv >= 4) RW(wv - 4, h);
    __syncthreads();
    if (wv < 4)  RA(wv, h);
  }
#pragma unroll
  for (int h = 0; h < 2; ++h){
    __syncthreads();
    if (wv == 2 || wv == 3) RW(wv - 2, h);
    __syncthreads();
    if (wv < 2)  RA(wv, h);
  }
#pragma unroll
  for (int h = 0; h < 2; ++h){
    __syncthreads();
    if (wv == 1) RW(0, h);
    __syncthreads();
    if (wv == 0) RA(0, h);
  }
#undef RW
#undef RA

  if (wv == 0){
    const float4 bia0 = *(const float4*)(bias + n0 + tx*8);
    const float4 bia1 = *(const float4*)(bias + n0 + tx*8 + 4);
#pragma unroll
    for (int i = 0; i < 8; i++){
      int row = mbase + ty*8 + i;
      if (row < r1){
        float* crow = C + (long long)row * N + n0 + tx*8;
        float4 v0, v1;
        v0.x = fmaxf(acc[i][0] + bia0.x, 0.f); v0.y = fmaxf(acc[i][1] + bia0.y, 0.f);
        v0.z = fmaxf(acc[i][2] + bia0.z, 0.f); v0.w = fmaxf(acc[i][3] + bia0.w, 0.f);
        v1.x = fmaxf(acc[i][4] + bia1.x, 0.f); v1.y = fmaxf(acc[i][5] + bia1.y, 0.f);
        v1.z = fmaxf(acc[i][6] + bia1.z, 0.f); v1.w = fmaxf(acc[i][7] + bia1.w, 0.f);
        *(float4*)(crow) = v0;
        *(float4*)(crow + 4) = v1;
      }
    }
  }
}

// ---------------- per-row head: opt logits + softmax + argmax + gumbel sel + termination ----------------
__global__ __launch_bounds__(256)
void head_kernel(const float* __restrict__ h1, const float* __restrict__ th,
                 const float* __restrict__ ow2, const float* __restrict__ ob2,
                 const float* __restrict__ tw2, const float* __restrict__ tb2,
                 float* __restrict__ out, int* __restrict__ sel)
{
  const int b = blockIdx.x;
  const int t = threadIdx.x;
  const float* hrow = h1 + b * Hdim;
  const float* trow = th + b * Hdim;

  float acc[8] = {}; float accT = 0.f;
  for (int k = t; k < Hdim; k += 256){
    float hv = hrow[k];
    const float* w = ow2 + k * 8;
#pragma unroll
    for (int o2 = 0; o2 < 8; ++o2) acc[o2] += hv * w[o2];
    accT += trow[k] * tw2[k];
  }
#pragma unroll
  for (int o2 = 0; o2 < 8; ++o2)
    for (int off = 32; off; off >>= 1) acc[o2] += __shfl_down(acc[o2], off);
  for (int off = 32; off; off >>= 1) accT += __shfl_down(accT, off);

  __shared__ float wred[4][9];
  __shared__ float logits[8];
  __shared__ float gum[8];
  const int wave = t >> 6, lane = t & 63;
  if (lane == 0){
#pragma unroll
    for (int o2 = 0; o2 < 8; ++o2) wred[wave][o2] = acc[o2];
    wred[wave][8] = accT;
  }
  __syncthreads();
  if (t < 9){
    float s = wred[0][t] + wred[1][t] + wred[2][t] + wred[3][t];
    if (t < 8) logits[t] = s + ob2[t];
    else       out[OFF_TERM + b] = 1.f / (1.f + expf(-(s + tb2[0])));
  }
  __syncthreads();
  if (t < 8) gum[t] = logits[t] + gumbel_at(b * 8 + t);
  __syncthreads();
  if (t == 0){
    float m = logits[0]; int am = 0;
#pragma unroll
    for (int o2 = 1; o2 < 8; ++o2) if (logits[o2] > m){ m = logits[o2]; am = o2; }
    float p[8]; float s = 0.f;
#pragma unroll
    for (int o2 = 0; o2 < 8; ++o2){ p[o2] = expf(logits[o2] - m); s += p[o2]; }
    float inv = 1.f / s;
#pragma unroll
    for (int o2 = 0; o2 < 8; ++o2) out[b * 8 + o2] = p[o2] * inv;
    out[OFF_OARG + b] = (float)am;
    float gm = gum[0]; int gs = 0;
#pragma unroll
    for (int o2 = 1; o2 < 8; ++o2) if (gum[o2] > gm){ gm = gum[o2]; gs = o2; }
    sel[b] = gs;
  }
}

// ---------------- routing: bucket samples by expert + emit row-tile list ----------------
__global__ void route_kernel(const int* __restrict__ sel, int* __restrict__ order,
                             int* __restrict__ offsets, int* __restrict__ tlist)
{
  __shared__ int cnt[8];
  __shared__ int base[8];
  const int t = threadIdx.x;
  if (t < 8) cnt[t] = 0;
  __syncthreads();
  const int s = sel[t];
  atomicAdd(&cnt[s], 1);
  __syncthreads();
  if (t == 0){
    int a = 0;
    for (int o = 0; o < 8; ++o){ offsets[o] = a; base[o] = a; a += cnt[o]; }
    offsets[8] = a;
    int nt = 0;
    for (int o = 0; o < 8; ++o)
      for (int mb = offsets[o]; mb < offsets[o] + cnt[o]; mb += 64){
        tlist[1 + 2*nt] = o; tlist[2 + 2*nt] = mb; ++nt;
      }
    tlist[0] = nt;
  }
  __syncthreads();
  const int pos = atomicAdd(&base[s], 1);
  order[pos] = t;   // permutation within an expert is nondeterministic; outputs don't depend on it
}

// ---------------- per-row output head: q = h2 @ awo + abo, softmax, argmax ----------------
__global__ __launch_bounds__(256)
void expert_out_kernel(const float* __restrict__ he2, const float* __restrict__ awo,
                       const float* __restrict__ abo,
                       const int* __restrict__ order, const int* __restrict__ offsets,
                       float* __restrict__ out)
{
  const int r = blockIdx.x;
  int o = 0;
#pragma unroll
  for (int i = 1; i < 8; ++i) if (offsets[i] <= r) o = i;
  const int t = threadIdx.x;
  const int a = t & 63, kg = t >> 6;
  const float* hrow = he2 + r * Hdim;
  const float* W = awo + o * Hdim * Aact;
  float acc = 0.f;
  const int k0 = kg * 256;
  for (int k = k0; k < k0 + 256; ++k) acc += hrow[k] * W[k * Aact + a];
  __shared__ float redm[4][64];
  redm[kg][a] = acc;
  __syncthreads();
  if (t < 64){
    float q = redm[0][a] + redm[1][a] + redm[2][a] + redm[3][a] + abo[o * Aact + a];
    float m = q;
#pragma unroll
    for (int off = 32; off; off >>= 1) m = fmaxf(m, __shfl_xor(m, off));
    float e = expf(q - m);
    float s = e;
#pragma unroll
    for (int off = 32; off; off >>= 1) s += __shfl_xor(s, off);
    const int b = order[r];
    out[OFF_ACT + b * Aact + a] = e / s;
    unsigned long long msk = __ballot(q == m);
    if (a == 0) out[OFF_SACT + b] = (float)__builtin_ctzll(msk);
  }
}

extern "C" void kernel_launch(void* const* d_in, const int* in_sizes, int n_in,
                              void* d_out, int out_size, void* d_ws, size_t ws_size,
                              hipStream_t stream)
{
  (void)in_sizes; (void)n_in; (void)out_size; (void)ws_size;
  const float* state = (const float*)d_in[0];
  const float* ow1   = (const float*)d_in[1];
  const float* ob1   = (const float*)d_in[2];
  const float* ow2   = (const float*)d_in[3];
  const float* ob2   = (const float*)d_in[4];
  const float* aw1   = (const float*)d_in[5];
  const float* ab1   = (const float*)d_in[6];
  const float* awh   = (const float*)d_in[7];
  const float* abh   = (const float*)d_in[8];
  const float* awo   = (const float*)d_in[9];
  const float* abo   = (const float*)d_in[10];
  const float* tw1   = (const float*)d_in[11];
  const float* tb1   = (const float*)d_in[12];
  const float* tw2   = (const float*)d_in[13];
  const float* tb2   = (const float*)d_in[14];
  float* out = (float*)d_out;

  float* h1 = (float*)d_ws;             // opt hidden -> expert L1 out (permuted rows)
  float* h2 = h1 + Bsz * Hdim;          // term hidden -> expert L2 out (permuted rows)
  int* sel     = (int*)(h2 + Bsz * Hdim);
  int* order   = sel + Bsz;
  int* offsets = order + Bsz;
  int* tlist   = offsets + 9;           // [ntiles | (expert,mbase) * MAXT]

  // dense pair (opt+term hidden): z=0 -> h1, z=1 -> h2
  gemm_splitk8<false,true><<<dim3(16,16,2), 512, 0, stream>>>(
      state, Din, ow1, tw1, 0, ob1, tb1, 0, h1, h2, Hdim, Din, nullptr, nullptr, nullptr);
  // heads: opt softmax/argmax, gumbel categorical sel, termination sigmoid
  head_kernel<<<dim3(Bsz), 256, 0, stream>>>(h1, h2, ow2, ob2, tw2, tb2, out, sel);
  // bucket samples by expert + tile list
  route_kernel<<<dim3(1), 1024, 0, stream>>>(sel, order, offsets, tlist);
  // expert L1 (gather state rows): h1[r] = relu(state[order[r]] @ aw1[o] + ab1[o])
  gemm_splitk8<true,false><<<dim3(MAXT,16,1), 512, 0, stream>>>(
      state, Din, aw1, nullptr, (long long)Din*Hdim, ab1, nullptr, Hdim,
      h1, nullptr, Hdim, Din, order, offsets, tlist);
  // expert L2: h2[r] = relu(h1[r] @ awh[o,0] + abh[o,0])
  gemm_splitk8<false,false><<<dim3(MAXT,16,1), 512, 0, stream>>>(
      h1, Hdim, awh, nullptr, (long long)Hdim*Hdim, abh, nullptr, Hdim,
      h2, nullptr, Hdim, Hdim, nullptr, offsets, tlist);
  // output head: q, action softmax, selected action
  expert_out_kernel<<<dim3(Bsz), 256, 0, stream>>>(h2, awo, abo, order, offsets, out);
}

// Round 13
// 209.206 us; speedup vs baseline: 1.0751x; 1.0751x over previous
//
#include <hip/hip_runtime.h>
#include <math.h>

#define Bsz 1024
#define Din 512
#define Hdim 1024
#define Aact 64
#define MAXT 23   // max row-tiles across experts: 7 partial + 16
#define NXCD 8

// out layout (float32): option_probs[1024*8] | action_probs[1024*64] | term[1024] | opt_argmax[1024] | sel_action[1024]
#define OFF_ACT   8192
#define OFF_TERM  73728
#define OFF_OARG  74752
#define OFF_SACT  75776

// ---------------- threefry2x32-20, key (0,42), partitionable XOR-fold (verified R3-R12) ----------------
__device__ __forceinline__ unsigned rotl32(unsigned x, int d){ return (x << d) | (x >> (32 - d)); }

__device__ __forceinline__ void threefry_042(unsigned& x0, unsigned& x1){
  const unsigned ks0 = 0u, ks1 = 42u, ks2 = 0x1BD11BDAu ^ 0u ^ 42u;
  x0 += ks0; x1 += ks1;
#define TFR(r) { x0 += x1; x1 = rotl32(x1, r); x1 ^= x0; }
  TFR(13) TFR(15) TFR(26) TFR(6)  x0 += ks1; x1 += ks2 + 1u;
  TFR(17) TFR(29) TFR(16) TFR(24) x0 += ks2; x1 += ks0 + 2u;
  TFR(13) TFR(15) TFR(26) TFR(6)  x0 += ks0; x1 += ks1 + 3u;
  TFR(17) TFR(29) TFR(16) TFR(24) x0 += ks1; x1 += ks2 + 4u;
  TFR(13) TFR(15) TFR(26) TFR(6)  x0 += ks2; x1 += ks0 + 5u;
#undef TFR
}

__device__ __forceinline__ float gumbel_at(int idx){
  unsigned x0 = 0u, x1 = (unsigned)idx;
  threefry_042(x0, x1);
  unsigned bits = x0 ^ x1;
  float f = __uint_as_float((bits >> 9) | 0x3F800000u) - 1.0f;
  float u = fmaxf(f, 1.1754944e-38f);
  return -logf(-logf(u));
}

// ---------------- 64x64 transpose (optionally row-gathered): out[k][r] = in[ord(r)][k] ----------------
// in [R][C] row-major, out [C][R]. grid (R/64, C/64), 256 threads.
__global__ __launch_bounds__(256)
void transpose_kernel(const float* __restrict__ in, int C, int R,
                      float* __restrict__ outp, const int* __restrict__ order)
{
  __shared__ float t[64][65];
  const int rt = blockIdx.x * 64, kt = blockIdx.y * 64;
  const int tr = threadIdx.x >> 4;          // 0..15
  const int tc = (threadIdx.x & 15) * 4;    // 0..60
#pragma unroll
  for (int i = 0; i < 4; i++){
    int r = rt + tr + i * 16;
    int ridx = order ? order[r] : r;
    float4 v = *(const float4*)(in + (long long)ridx * C + kt + tc);
    t[tr + i*16][tc + 0] = v.x; t[tr + i*16][tc + 1] = v.y;
    t[tr + i*16][tc + 2] = v.z; t[tr + i*16][tc + 3] = v.w;
  }
  __syncthreads();
#pragma unroll
  for (int i = 0; i < 4; i++){
    int kl = tr + i * 16;
    float4 v;
    v.x = t[tc + 0][kl]; v.y = t[tc + 1][kl];
    v.z = t[tc + 2][kl]; v.w = t[tc + 3][kl];
    *(float4*)(outp + (long long)(kt + kl) * R + rt + tc) = v;
  }
}

// ---------------- 64x64 tile GEMM on TRANSPOSED A (AT [K][M]), 8 waves split-K, 8x8/thread --------
// R13: A-loads now row-contiguous like B (2 x b128, 16-line) — R5..R12 all pinned at 77-88us with
// VALUBusy ~22% regardless of structure; the invariant was A's 64-line-per-instr row gather
// (per-lane sample rows 2-4KB apart). AT layout kills the gather; A LDS staging becomes 2 b128 writes.
// K-loop waits = R10's proven structure. Reduce = R10 stride-67 (0 conflicts). TRANSC: epilogue
// writes C transposed ([N][M]) — same 16-store cost via the symmetric 8x8 register tile.
template<bool TRANSC, bool DENSE>
__global__ __launch_bounds__(512)
void gemm_splitk8(const float* __restrict__ AT,
                  const float* __restrict__ W0, const float* __restrict__ W1,
                  long long wstride,
                  const float* __restrict__ b0, const float* __restrict__ b1,
                  int bstride,
                  float* __restrict__ C0, float* __restrict__ C1,
                  int N, int K,
                  const int* __restrict__ offsets, const int* __restrict__ tlist)
{
  const float* W; const float* bias; float* C;
  int mbase, r1, n0;
  if (DENSE){
    const int bid = (int)(blockIdx.x + gridDim.x * (blockIdx.y + gridDim.y * blockIdx.z)); // 0..511
    const int wf = (bid % NXCD) * (512 / NXCD) + bid / NXCD;   // bijective (512%8==0)
    const int ny = wf & 15, mx = (wf >> 4) & 15, z = wf >> 8;
    mbase = mx * 64; r1 = Bsz; n0 = ny * 64;
    W = z ? W1 : W0; bias = z ? b1 : b0; C = z ? C1 : C0;
  } else {
    const int bid = (int)(blockIdx.x + gridDim.x * blockIdx.y); // 368 = 46*8, bijective
    const int wf = (bid % NXCD) * ((MAXT * 16) / NXCD) + bid / NXCD;
    const int i = wf >> 4;
    if (i >= tlist[0]) return;
    const int o = tlist[1 + 2*i];
    mbase = tlist[2 + 2*i];
    r1 = offsets[o + 1];
    n0 = (wf & 15) * 64;
    W = W0 + (long long)o * wstride; bias = b0 + o * bstride; C = C0;
  }

  __shared__ float lds[17408];   // staging: 8 waves x 1024; reduce: 4 x 4288 (overlaid after K-loop)

  const int tid = threadIdx.x;
  const int wv = tid >> 6, lane = tid & 63;
  const int ty = lane >> 3, tx = lane & 7;
  const int KC = K >> 3, NT = KC >> 3;      // per-wave K chunk; 8-k sub-tiles
  const int k0 = wv * KC;
  const int bkr = lane >> 4;                // base k-row (0..3)
  const int bnc = (lane & 15) * 4;          // column quad

  const float* Ap = AT + (long long)k0 * Bsz + mbase + bnc;   // AT is [K][1024]
  const float* Wp = W + (long long)k0 * N + n0 + bnc;

  float* myst = lds + wv * 1024;            // [As 8x64 | Bs 8x64]

  float acc[8][8];
#pragma unroll
  for (int i = 0; i < 8; i++)
#pragma unroll
    for (int j = 0; j < 8; j++) acc[i][j] = 0.f;

  float4 a4[2], b4[2];

#define LOADT(it) {                                                          \
    _Pragma("unroll")                                                        \
    for (int r = 0; r < 2; r++)                                              \
      a4[r] = *(const float4*)(Ap + (long long)((it) * 8 + bkr + r*4) * Bsz);\
    _Pragma("unroll")                                                        \
    for (int r = 0; r < 2; r++)                                              \
      b4[r] = *(const float4*)(Wp + (long long)((it) * 8 + bkr + r*4) * N); }

#define STORET() {                                                           \
    float* As = myst;                                                        \
    float* Bs = myst + 512;                                                  \
    _Pragma("unroll")                                                        \
    for (int r = 0; r < 2; r++)                                              \
      *(float4*)(As + (bkr + r*4)*64 + bnc) = a4[r];                         \
    _Pragma("unroll")                                                        \
    for (int r = 0; r < 2; r++)                                              \
      *(float4*)(Bs + (bkr + r*4)*64 + bnc) = b4[r]; }

  LOADT(0); STORET(); LOADT(1);
  asm volatile("s_waitcnt lgkmcnt(0)" ::: "memory");

  for (int it = 0; it < NT; ++it){
    const float* As = myst;
    const float* Bs = myst + 512;
#pragma unroll
    for (int kk = 0; kk < 8; ++kk){
      float4 av0 = *(const float4*)(As + kk*64 + ty*8);
      float4 av1 = *(const float4*)(As + kk*64 + ty*8 + 4);
      float4 bv0 = *(const float4*)(Bs + kk*64 + tx*8);
      float4 bv1 = *(const float4*)(Bs + kk*64 + tx*8 + 4);
      float a[8] = {av0.x,av0.y,av0.z,av0.w,av1.x,av1.y,av1.z,av1.w};
      float b[8] = {bv0.x,bv0.y,bv0.z,bv0.w,bv1.x,bv1.y,bv1.z,bv1.w};
#pragma unroll
      for (int i = 0; i < 8; i++)
#pragma unroll
        for (int j = 0; j < 8; j++) acc[i][j] = fmaf(a[i], b[j], acc[i][j]);
    }
    if (it + 1 < NT){
      asm volatile("s_waitcnt lgkmcnt(0)" ::: "memory");  // reads retired before overwrite
      STORET();                                           // (compiler inserts vmcnt for a4/b4)
      if (it + 2 < NT) LOADT(it + 2);
      asm volatile("s_waitcnt lgkmcnt(0)" ::: "memory");  // stores landed before next compute
    }
  }
#undef LOADT
#undef STORET

  // ---- log-tree cross-wave reduce: 8 -> 4 -> 2 -> 1 (stride 67, proven 0-conflict in R10/R11) ----
#define RWRITE(w) { float* r = lds + (w) * 4288 + lane * 67;                 \
    _Pragma("unroll")                                                        \
    for (int i = 0; i < 8; i++)                                              \
      _Pragma("unroll")                                                      \
      for (int j = 0; j < 8; j++) r[i*8 + j] = acc[i][j]; }
#define RADD(w) { const float* r = lds + (w) * 4288 + lane * 67;             \
    _Pragma("unroll")                                                        \
    for (int i = 0; i < 8; i++)                                              \
      _Pragma("unroll")                                                      \
      for (int j = 0; j < 8; j++) acc[i][j] += r[i*8 + j]; }

  __syncthreads();
  if (wv >= 4) RWRITE(wv - 4);
  __syncthreads();
  if (wv < 4)  RADD(wv);
  __syncthreads();
  if (wv == 2 || wv == 3) RWRITE(wv - 2);
  __syncthreads();
  if (wv < 2)  RADD(wv);
  __syncthreads();
  if (wv == 1) RWRITE(0);
  __syncthreads();
  if (wv == 0){
    RADD(0);
    if (!TRANSC){
#pragma unroll
      for (int i = 0; i < 8; i++){
        int row = mbase + ty*8 + i;
        if (row < r1){
          float* crow = C + (long long)row * N + n0 + tx*8;
#pragma unroll
          for (int j = 0; j < 8; j++)
            crow[j] = fmaxf(acc[i][j] + bias[n0 + tx*8 + j], 0.0f);
        }
      }
    } else {
      // C transposed: CT[N][1024]; CT[col][row] = relu(acc + bias[col])
#pragma unroll
      for (int j = 0; j < 8; j++){
        const int col = n0 + tx*8 + j;
        const float bj = bias[col];
        float* cb = C + (long long)col * Bsz + mbase + ty*8;
        if (mbase + ty*8 + 7 < r1){
          float4 v0, v1;
          v0.x = fmaxf(acc[0][j] + bj, 0.f); v0.y = fmaxf(acc[1][j] + bj, 0.f);
          v0.z = fmaxf(acc[2][j] + bj, 0.f); v0.w = fmaxf(acc[3][j] + bj, 0.f);
          v1.x = fmaxf(acc[4][j] + bj, 0.f); v1.y = fmaxf(acc[5][j] + bj, 0.f);
          v1.z = fmaxf(acc[6][j] + bj, 0.f); v1.w = fmaxf(acc[7][j] + bj, 0.f);
          *(float4*)cb = v0; *(float4*)(cb + 4) = v1;
        } else {
#pragma unroll
          for (int i = 0; i < 8; i++)
            if (mbase + ty*8 + i < r1) cb[i] = fmaxf(acc[i][j] + bj, 0.f);
        }
      }
    }
  }
#undef RWRITE
#undef RADD
}

// ---------------- per-row head: opt logits + softmax + argmax + gumbel sel + termination ----------------
__global__ __launch_bounds__(256)
void head_kernel(const float* __restrict__ h1, const float* __restrict__ th,
                 const float* __restrict__ ow2, const float* __restrict__ ob2,
                 const float* __restrict__ tw2, const float* __restrict__ tb2,
                 float* __restrict__ out, int* __restrict__ sel)
{
  const int b = blockIdx.x;
  const int t = threadIdx.x;
  const float* hrow = h1 + b * Hdim;
  const float* trow = th + b * Hdim;

  float acc[8] = {}; float accT = 0.f;
  for (int k = t; k < Hdim; k += 256){
    float hv = hrow[k];
    const float* w = ow2 + k * 8;
#pragma unroll
    for (int o2 = 0; o2 < 8; ++o2) acc[o2] += hv * w[o2];
    accT += trow[k] * tw2[k];
  }
#pragma unroll
  for (int o2 = 0; o2 < 8; ++o2)
    for (int off = 32; off; off >>= 1) acc[o2] += __shfl_down(acc[o2], off);
  for (int off = 32; off; off >>= 1) accT += __shfl_down(accT, off);

  __shared__ float wred[4][9];
  __shared__ float logits[8];
  __shared__ float gum[8];
  const int wave = t >> 6, lane = t & 63;
  if (lane == 0){
#pragma unroll
    for (int o2 = 0; o2 < 8; ++o2) wred[wave][o2] = acc[o2];
    wred[wave][8] = accT;
  }
  __syncthreads();
  if (t < 9){
    float s = wred[0][t] + wred[1][t] + wred[2][t] + wred[3][t];
    if (t < 8) logits[t] = s + ob2[t];
    else       out[OFF_TERM + b] = 1.f / (1.f + expf(-(s + tb2[0])));
  }
  __syncthreads();
  if (t < 8) gum[t] = logits[t] + gumbel_at(b * 8 + t);
  __syncthreads();
  if (t == 0){
    float m = logits[0]; int am = 0;
#pragma unroll
    for (int o2 = 1; o2 < 8; ++o2) if (logits[o2] > m){ m = logits[o2]; am = o2; }
    float p[8]; float s = 0.f;
#pragma unroll
    for (int o2 = 0; o2 < 8; ++o2){ p[o2] = expf(logits[o2] - m); s += p[o2]; }
    float inv = 1.f / s;
#pragma unroll
    for (int o2 = 0; o2 < 8; ++o2) out[b * 8 + o2] = p[o2] * inv;
    out[OFF_OARG + b] = (float)am;
    float gm = gum[0]; int gs = 0;
#pragma unroll
    for (int o2 = 1; o2 < 8; ++o2) if (gum[o2] > gm){ gm = gum[o2]; gs = o2; }
    sel[b] = gs;
  }
}

// ---------------- routing: bucket samples by expert + emit row-tile list ----------------
__global__ void route_kernel(const int* __restrict__ sel, int* __restrict__ order,
                             int* __restrict__ offsets, int* __restrict__ tlist)
{
  __shared__ int cnt[8];
  __shared__ int base[8];
  const int t = threadIdx.x;
  if (t < 8) cnt[t] = 0;
  __syncthreads();
  const int s = sel[t];
  atomicAdd(&cnt[s], 1);
  __syncthreads();
  if (t == 0){
    int a = 0;
    for (int o = 0; o < 8; ++o){ offsets[o] = a; base[o] = a; a += cnt[o]; }
    offsets[8] = a;
    int nt = 0;
    for (int o = 0; o < 8; ++o)
      for (int mb = offsets[o]; mb < offsets[o] + cnt[o]; mb += 64){
        tlist[1 + 2*nt] = o; tlist[2 + 2*nt] = mb; ++nt;
      }
    tlist[0] = nt;
  }
  __syncthreads();
  const int pos = atomicAdd(&base[s], 1);
  order[pos] = t;   // permutation within an expert is nondeterministic; outputs don't depend on it
}

// ---------------- per-row output head: q = h2 @ awo + abo, softmax, argmax ----------------
__global__ __launch_bounds__(256)
void expert_out_kernel(const float* __restrict__ he2, const float* __restrict__ awo,
                       const float* __restrict__ abo,
                       const int* __restrict__ order, const int* __restrict__ offsets,
                       float* __restrict__ out)
{
  const int r = blockIdx.x;
  int o = 0;
#pragma unroll
  for (int i = 1; i < 8; ++i) if (offsets[i] <= r) o = i;
  const int t = threadIdx.x;
  const int a = t & 63, kg = t >> 6;
  const float* hrow = he2 + r * Hdim;
  const float* W = awo + o * Hdim * Aact;
  float acc = 0.f;
  const int k0 = kg * 256;
  for (int k = k0; k < k0 + 256; ++k) acc += hrow[k] * W[k * Aact + a];
  __shared__ float redm[4][64];
  redm[kg][a] = acc;
  __syncthreads();
  if (t < 64){
    float q = redm[0][a] + redm[1][a] + redm[2][a] + redm[3][a] + abo[o * Aact + a];
    float m = q;
#pragma unroll
    for (int off = 32; off; off >>= 1) m = fmaxf(m, __shfl_xor(m, off));
    float e = expf(q - m);
    float s = e;
#pragma unroll
    for (int off = 32; off; off >>= 1) s += __shfl_xor(s, off);
    const int b = order[r];
    out[OFF_ACT + b * Aact + a] = e / s;
    unsigned long long msk = __ballot(q == m);
    if (a == 0) out[OFF_SACT + b] = (float)__builtin_ctzll(msk);
  }
}

extern "C" void kernel_launch(void* const* d_in, const int* in_sizes, int n_in,
                              void* d_out, int out_size, void* d_ws, size_t ws_size,
                              hipStream_t stream)
{
  (void)in_sizes; (void)n_in; (void)out_size; (void)ws_size;
  const float* state = (const float*)d_in[0];
  const float* ow1   = (const float*)d_in[1];
  const float* ob1   = (const float*)d_in[2];
  const float* ow2   = (const float*)d_in[3];
  const float* ob2   = (const float*)d_in[4];
  const float* aw1   = (const float*)d_in[5];
  const float* ab1   = (const float*)d_in[6];
  const float* awh   = (const float*)d_in[7];
  const float* abh   = (const float*)d_in[8];
  const float* awo   = (const float*)d_in[9];
  const float* abo   = (const float*)d_in[10];
  const float* tw1   = (const float*)d_in[11];
  const float* tb1   = (const float*)d_in[12];
  const float* tw2   = (const float*)d_in[13];
  const float* tb2   = (const float*)d_in[14];
  float* out = (float*)d_out;

  float* h1  = (float*)d_ws;            // [1024][1024] dense opt-hidden; later reused as h1T [H][1024]
  float* h2  = h1 + Bsz * Hdim;         // [1024][1024] dense term-hidden; later L2 out (row-major)
  float* stT = h2 + Bsz * Hdim;         // [512][1024] state^T (plain); later reused as stTP (permuted)
  int* sel     = (int*)(stT + Din * Bsz);
  int* order   = sel + Bsz;
  int* offsets = order + Bsz;
  int* tlist   = offsets + 9;           // [ntiles | (expert,mbase) * MAXT]

  // 1. state [1024][512] -> stT [512][1024]
  transpose_kernel<<<dim3(16, 8), 256, 0, stream>>>(state, Din, Bsz, stT, nullptr);
  // 2. dense pair (opt+term hidden): z=0 -> h1, z=1 -> h2 (row-major)
  gemm_splitk8<false, true><<<dim3(16,16,2), 512, 0, stream>>>(
      stT, ow1, tw1, 0, ob1, tb1, 0, h1, h2, Hdim, Din, nullptr, nullptr);
  // 3. heads: opt softmax/argmax, gumbel categorical sel, termination sigmoid
  head_kernel<<<dim3(Bsz), 256, 0, stream>>>(h1, h2, ow2, ob2, tw2, tb2, out, sel);
  // 4. bucket samples by expert + tile list
  route_kernel<<<dim3(1), 1024, 0, stream>>>(sel, order, offsets, tlist);
  // 5. permuted transpose: stTP[k][r] = state[order[r]][k]  (reuses stT buffer)
  transpose_kernel<<<dim3(16, 8), 256, 0, stream>>>(state, Din, Bsz, stT, order);
  // 6. expert L1: h1T[col][r] = relu(stTP-row r @ aw1[o] + ab1[o])  (TRANSC, reuses h1 buffer)
  gemm_splitk8<true, false><<<dim3(MAXT,16), 512, 0, stream>>>(
      stT, aw1, nullptr, (long long)Din*Hdim, ab1, nullptr, Hdim,
      h1, nullptr, Hdim, Din, offsets, tlist);
  // 7. expert L2: h2[r][col] = relu(h1T-col r @ awh[o,0] + abh[o,0])  (row-major out)
  gemm_splitk8<false, false><<<dim3(MAXT,16), 512, 0, stream>>>(
      h1, awh, nullptr, (long long)Hdim*Hdim, abh, nullptr, Hdim,
      h2, nullptr, Hdim, Hdim, offsets, tlist);
  // 8. output head: q, action softmax, selected action
  expert_out_kernel<<<dim3(Bsz), 256, 0, stream>>>(h2, awo, abo, order, offsets, out);
}

// Round 15
// 157.310 us; speedup vs baseline: 1.4298x; 1.3299x over previous
//
#include <hip/hip_runtime.h>
#include <math.h>

#define Bsz 1024
#define Din 512
#define Hdim 1024
#define Aact 64
#define MAXT 23   // max row-tiles across experts: 7 partial + 16
#define NXCD 8

// out layout (float32): option_probs[1024*8] | action_probs[1024*64] | term[1024] | opt_argmax[1024] | sel_action[1024]
#define OFF_ACT   8192
#define OFF_TERM  73728
#define OFF_OARG  74752
#define OFF_SACT  75776

// ---------------- threefry2x32-20, key (0,42), partitionable XOR-fold (verified R3-R13) ----------------
__device__ __forceinline__ unsigned rotl32(unsigned x, int d){ return (x << d) | (x >> (32 - d)); }

__device__ __forceinline__ void threefry_042(unsigned& x0, unsigned& x1){
  const unsigned ks0 = 0u, ks1 = 42u, ks2 = 0x1BD11BDAu ^ 0u ^ 42u;
  x0 += ks0; x1 += ks1;
#define TFR(r) { x0 += x1; x1 = rotl32(x1, r); x1 ^= x0; }
  TFR(13) TFR(15) TFR(26) TFR(6)  x0 += ks1; x1 += ks2 + 1u;
  TFR(17) TFR(29) TFR(16) TFR(24) x0 += ks2; x1 += ks0 + 2u;
  TFR(13) TFR(15) TFR(26) TFR(6)  x0 += ks0; x1 += ks1 + 3u;
  TFR(17) TFR(29) TFR(16) TFR(24) x0 += ks1; x1 += ks2 + 4u;
  TFR(13) TFR(15) TFR(26) TFR(6)  x0 += ks2; x1 += ks0 + 5u;
#undef TFR
}

__device__ __forceinline__ float gumbel_at(int idx){
  unsigned x0 = 0u, x1 = (unsigned)idx;
  threefry_042(x0, x1);
  unsigned bits = x0 ^ x1;
  float f = __uint_as_float((bits >> 9) | 0x3F800000u) - 1.0f;
  float u = fmaxf(f, 1.1754944e-38f);
  return -logf(-logf(u));
}

// ---------------- 64x64 tile GEMM, 4 independent waves = split-K x4, 8x8/thread ----------------
// R15 = R11's PROVEN kernel (loop/waits/staging verbatim) with SPLIT 8->4 and 256-thread blocks.
// Rationale: R11 OccupancyPercent ~12% (~4 waves/CU avg) — 512-thr/68KB blocks quantize to
// 2 blocks/CU with bad drain. 4-wave blocks: LDS 34.3KB -> 4 blocks/CU, VGPR ~116 -> 4 waves/SIMD,
// finer grid absorbs grouped-grid imbalance. No occupancy hints (R6/R7/R9: forced hints spill).
template<bool GATHER, bool DENSE>
__global__ __launch_bounds__(256)
void gemm_splitk4(const float* __restrict__ A, int lda,
                  const float* __restrict__ W0, const float* __restrict__ W1,
                  long long wstride,
                  const float* __restrict__ b0, const float* __restrict__ b1,
                  int bstride,
                  float* __restrict__ C0, float* __restrict__ C1,
                  int N, int K,
                  const int* __restrict__ order, const int* __restrict__ offsets,
                  const int* __restrict__ tlist)
{
  const float* W; const float* bias; float* C;
  int mbase, r1, n0;
  if (DENSE){
    const int bid = (int)(blockIdx.x + gridDim.x * (blockIdx.y + gridDim.y * blockIdx.z)); // 0..511
    const int wf = (bid % NXCD) * (512 / NXCD) + bid / NXCD;   // bijective XCD swizzle (512%8==0)
    const int ny = wf & 15, mx = (wf >> 4) & 15, z = wf >> 8;
    mbase = mx * 64; r1 = Bsz; n0 = ny * 64;
    W = z ? W1 : W0; bias = z ? b1 : b0; C = z ? C1 : C0;
  } else {
    const int bid = (int)(blockIdx.x + gridDim.x * blockIdx.y); // 368 = 46*8, bijective
    const int wf = (bid % NXCD) * ((MAXT * 16) / NXCD) + bid / NXCD;
    const int i = wf >> 4;
    if (i >= tlist[0]) return;
    const int o = tlist[1 + 2*i];
    mbase = tlist[2 + 2*i];
    r1 = offsets[o + 1];
    n0 = (wf & 15) * 64;
    W = W0 + (long long)o * wstride; bias = b0 + o * bstride; C = C0;
  }

  __shared__ float lds[8576];   // staging: 4 waves x 1024; reduce: 2 x 4288 (overlaid after K-loop)

  const int tid = threadIdx.x;
  const int wv = tid >> 6, lane = tid & 63;
  const int ty = lane >> 3, tx = lane & 7;
  const int KC = K >> 2, NT = KC >> 3;      // per-wave K chunk; 8-k sub-tiles
  const int k0 = wv * KC;
  const int bkr = lane >> 4;                // B: base k-row (0..3)
  const int bnc = (lane & 15) * 4;          // B: column quad

  int grow = mbase + lane;
  int arow = grow < r1 ? grow : mbase;
  if (GATHER) arow = order[arow];
  const float* Ap = A + (long long)arow * lda + k0;
  const float* Wp = W + (long long)k0 * N + n0 + bnc;

  float* myst = lds + wv * 1024;            // [As 8x64 | Bs 8x64]

  float acc[8][8];
#pragma unroll
  for (int i = 0; i < 8; i++)
#pragma unroll
    for (int j = 0; j < 8; j++) acc[i][j] = 0.f;

  float4 a4[2], b4[2];

#define LOADT(it) {                                                          \
    const float* ap = Ap + (it) * 8;                                         \
    a4[0] = *(const float4*)(ap + 0);  a4[1] = *(const float4*)(ap + 4);     \
    const float* wp = Wp + (long long)((it) * 8 + bkr) * N;                  \
    b4[0] = *(const float4*)(wp);                                            \
    b4[1] = *(const float4*)(wp + (long long)4 * N); }

#define STORET() {                                                           \
    float* As = myst;                                                        \
    float* Bs = myst + 512;                                                  \
    _Pragma("unroll")                                                        \
    for (int q = 0; q < 2; q++){                                             \
      As[(q*4 + 0)*64 + lane] = a4[q].x;                                     \
      As[(q*4 + 1)*64 + lane] = a4[q].y;                                     \
      As[(q*4 + 2)*64 + lane] = a4[q].z;                                     \
      As[(q*4 + 3)*64 + lane] = a4[q].w; }                                   \
    _Pragma("unroll")                                                        \
    for (int r = 0; r < 2; r++)                                              \
      *(float4*)(Bs + (bkr + r*4)*64 + bnc) = b4[r]; }

  LOADT(0); STORET(); LOADT(1);
  asm volatile("s_waitcnt lgkmcnt(0)" ::: "memory");

  for (int it = 0; it < NT; ++it){
    const float* As = myst;
    const float* Bs = myst + 512;
#pragma unroll
    for (int kk = 0; kk < 8; ++kk){
      float4 av0 = *(const float4*)(As + kk*64 + ty*8);
      float4 av1 = *(const float4*)(As + kk*64 + ty*8 + 4);
      float4 bv0 = *(const float4*)(Bs + kk*64 + tx*8);
      float4 bv1 = *(const float4*)(Bs + kk*64 + tx*8 + 4);
      float a[8] = {av0.x,av0.y,av0.z,av0.w,av1.x,av1.y,av1.z,av1.w};
      float b[8] = {bv0.x,bv0.y,bv0.z,bv0.w,bv1.x,bv1.y,bv1.z,bv1.w};
#pragma unroll
      for (int i = 0; i < 8; i++)
#pragma unroll
        for (int j = 0; j < 8; j++) acc[i][j] = fmaf(a[i], b[j], acc[i][j]);
    }
    if (it + 1 < NT){
      asm volatile("s_waitcnt lgkmcnt(0)" ::: "memory");  // reads retired before overwrite
      STORET();                                           // (compiler inserts vmcnt for a4/b4)
      if (it + 2 < NT) LOADT(it + 2);
      asm volatile("s_waitcnt lgkmcnt(0)" ::: "memory");  // stores landed before next compute
    }
  }
#undef LOADT
#undef STORET

  // ---- log-tree cross-wave reduce: 4 -> 2 -> 1 (stride 67, proven 0-conflict R10/R11) ----
#define RWRITE(w) { float* r = lds + (w) * 4288 + lane * 67;                 \
    _Pragma("unroll")                                                        \
    for (int i = 0; i < 8; i++)                                              \
      _Pragma("unroll")                                                      \
      for (int j = 0; j < 8; j++) r[i*8 + j] = acc[i][j]; }
#define RADD(w) { const float* r = lds + (w) * 4288 + lane * 67;             \
    _Pragma("unroll")                                                        \
    for (int i = 0; i < 8; i++)                                              \
      _Pragma("unroll")                                                      \
      for (int j = 0; j < 8; j++) acc[i][j] += r[i*8 + j]; }

  __syncthreads();
  if (wv == 2 || wv == 3) RWRITE(wv - 2);
  __syncthreads();
  if (wv < 2)  RADD(wv);
  __syncthreads();
  if (wv == 1) RWRITE(0);
  __syncthreads();
  if (wv == 0){
    RADD(0);
#pragma unroll
    for (int i = 0; i < 8; i++){
      int row = mbase + ty*8 + i;
      if (row < r1){
        float* crow = C + (long long)row * N + n0 + tx*8;
#pragma unroll
        for (int j = 0; j < 8; j++)
          crow[j] = fmaxf(acc[i][j] + bias[n0 + tx*8 + j], 0.0f);
      }
    }
  }
#undef RWRITE
#undef RADD
}

// ---------------- per-row head: opt logits + softmax + argmax + gumbel sel + termination ----------------
__global__ __launch_bounds__(256)
void head_kernel(const float* __restrict__ h1, const float* __restrict__ th,
                 const float* __restrict__ ow2, const float* __restrict__ ob2,
                 const float* __restrict__ tw2, const float* __restrict__ tb2,
                 float* __restrict__ out, int* __restrict__ sel)
{
  const int b = blockIdx.x;
  const int t = threadIdx.x;
  const float* hrow = h1 + b * Hdim;
  const float* trow = th + b * Hdim;

  float acc[8] = {}; float accT = 0.f;
  for (int k = t; k < Hdim; k += 256){
    float hv = hrow[k];
    const float* w = ow2 + k * 8;
#pragma unroll
    for (int o2 = 0; o2 < 8; ++o2) acc[o2] += hv * w[o2];
    accT += trow[k] * tw2[k];
  }
#pragma unroll
  for (int o2 = 0; o2 < 8; ++o2)
    for (int off = 32; off; off >>= 1) acc[o2] += __shfl_down(acc[o2], off);
  for (int off = 32; off; off >>= 1) accT += __shfl_down(accT, off);

  __shared__ float wred[4][9];
  __shared__ float logits[8];
  __shared__ float gum[8];
  const int wave = t >> 6, lane = t & 63;
  if (lane == 0){
#pragma unroll
    for (int o2 = 0; o2 < 8; ++o2) wred[wave][o2] = acc[o2];
    wred[wave][8] = accT;
  }
  __syncthreads();
  if (t < 9){
    float s = wred[0][t] + wred[1][t] + wred[2][t] + wred[3][t];
    if (t < 8) logits[t] = s + ob2[t];
    else       out[OFF_TERM + b] = 1.f / (1.f + expf(-(s + tb2[0])));
  }
  __syncthreads();
  if (t < 8) gum[t] = logits[t] + gumbel_at(b * 8 + t);
  __syncthreads();
  if (t == 0){
    float m = logits[0]; int am = 0;
#pragma unroll
    for (int o2 = 1; o2 < 8; ++o2) if (logits[o2] > m){ m = logits[o2]; am = o2; }
    float p[8]; float s = 0.f;
#pragma unroll
    for (int o2 = 0; o2 < 8; ++o2){ p[o2] = expf(logits[o2] - m); s += p[o2]; }
    float inv = 1.f / s;
#pragma unroll
    for (int o2 = 0; o2 < 8; ++o2) out[b * 8 + o2] = p[o2] * inv;
    out[OFF_OARG + b] = (float)am;
    float gm = gum[0]; int gs = 0;
#pragma unroll
    for (int o2 = 1; o2 < 8; ++o2) if (gum[o2] > gm){ gm = gum[o2]; gs = o2; }
    sel[b] = gs;
  }
}

// ---------------- routing: bucket samples by expert + emit row-tile list ----------------
__global__ void route_kernel(const int* __restrict__ sel, int* __restrict__ order,
                             int* __restrict__ offsets, int* __restrict__ tlist)
{
  __shared__ int cnt[8];
  __shared__ int base[8];
  const int t = threadIdx.x;
  if (t < 8) cnt[t] = 0;
  __syncthreads();
  const int s = sel[t];
  atomicAdd(&cnt[s], 1);
  __syncthreads();
  if (t == 0){
    int a = 0;
    for (int o = 0; o < 8; ++o){ offsets[o] = a; base[o] = a; a += cnt[o]; }
    offsets[8] = a;
    int nt = 0;
    for (int o = 0; o < 8; ++o)
      for (int mb = offsets[o]; mb < offsets[o] + cnt[o]; mb += 64){
        tlist[1 + 2*nt] = o; tlist[2 + 2*nt] = mb; ++nt;
      }
    tlist[0] = nt;
  }
  __syncthreads();
  const int pos = atomicAdd(&base[s], 1);
  order[pos] = t;   // permutation within an expert is nondeterministic; outputs don't depend on it
}

// ---------------- per-row output head: q = h2 @ awo + abo, softmax, argmax ----------------
__global__ __launch_bounds__(256)
void expert_out_kernel(const float* __restrict__ he2, const float* __restrict__ awo,
                       const float* __restrict__ abo,
                       const int* __restrict__ order, const int* __restrict__ offsets,
                       float* __restrict__ out)
{
  const int r = blockIdx.x;
  int o = 0;
#pragma unroll
  for (int i = 1; i < 8; ++i) if (offsets[i] <= r) o = i;
  const int t = threadIdx.x;
  const int a = t & 63, kg = t >> 6;
  const float* hrow = he2 + r * Hdim;
  const float* W = awo + o * Hdim * Aact;
  float acc = 0.f;
  const int k0 = kg * 256;
  for (int k = k0; k < k0 + 256; ++k) acc += hrow[k] * W[k * Aact + a];
  __shared__ float redm[4][64];
  redm[kg][a] = acc;
  __syncthreads();
  if (t < 64){
    float q = redm[0][a] + redm[1][a] + redm[2][a] + redm[3][a] + abo[o * Aact + a];
    float m = q;
#pragma unroll
    for (int off = 32; off; off >>= 1) m = fmaxf(m, __shfl_xor(m, off));
    float e = expf(q - m);
    float s = e;
#pragma unroll
    for (int off = 32; off; off >>= 1) s += __shfl_xor(s, off);
    const int b = order[r];
    out[OFF_ACT + b * Aact + a] = e / s;
    unsigned long long msk = __ballot(q == m);
    if (a == 0) out[OFF_SACT + b] = (float)__builtin_ctzll(msk);
  }
}

extern "C" void kernel_launch(void* const* d_in, const int* in_sizes, int n_in,
                              void* d_out, int out_size, void* d_ws, size_t ws_size,
                              hipStream_t stream)
{
  (void)in_sizes; (void)n_in; (void)out_size; (void)ws_size;
  const float* state = (const float*)d_in[0];
  const float* ow1   = (const float*)d_in[1];
  const float* ob1   = (const float*)d_in[2];
  const float* ow2   = (const float*)d_in[3];
  const float* ob2   = (const float*)d_in[4];
  const float* aw1   = (const float*)d_in[5];
  const float* ab1   = (const float*)d_in[6];
  const float* awh   = (const float*)d_in[7];
  const float* abh   = (const float*)d_in[8];
  const float* awo   = (const float*)d_in[9];
  const float* abo   = (const float*)d_in[10];
  const float* tw1   = (const float*)d_in[11];
  const float* tb1   = (const float*)d_in[12];
  const float* tw2   = (const float*)d_in[13];
  const float* tb2   = (const float*)d_in[14];
  float* out = (float*)d_out;

  float* h1 = (float*)d_ws;             // opt hidden -> expert L1 out (permuted rows)
  float* h2 = h1 + Bsz * Hdim;          // term hidden -> expert L2 out (permuted rows)
  int* sel     = (int*)(h2 + Bsz * Hdim);
  int* order   = sel + Bsz;
  int* offsets = order + Bsz;
  int* tlist   = offsets + 9;           // [ntiles | (expert,mbase) * MAXT]

  // dense pair (opt+term hidden): z=0 -> h1, z=1 -> h2
  gemm_splitk4<false,true><<<dim3(16,16,2), 256, 0, stream>>>(
      state, Din, ow1, tw1, 0, ob1, tb1, 0, h1, h2, Hdim, Din, nullptr, nullptr, nullptr);
  // heads: opt softmax/argmax, gumbel categorical sel, termination sigmoid
  head_kernel<<<dim3(Bsz), 256, 0, stream>>>(h1, h2, ow2, ob2, tw2, tb2, out, sel);
  // bucket samples by expert + tile list
  route_kernel<<<dim3(1), 1024, 0, stream>>>(sel, order, offsets, tlist);
  // expert L1 (gather state rows): h1[r] = relu(state[order[r]] @ aw1[o] + ab1[o])
  gemm_splitk4<true,false><<<dim3(MAXT,16), 256, 0, stream>>>(
      state, Din, aw1, nullptr, (long long)Din*Hdim, ab1, nullptr, Hdim,
      h1, nullptr, Hdim, Din, order, offsets, tlist);
  // expert L2: h2[r] = relu(h1[r] @ awh[o,0] + abh[o,0])
  gemm_splitk4<false,false><<<dim3(MAXT,16), 256, 0, stream>>>(
      h1, Hdim, awh, nullptr, (long long)Hdim*Hdim, abh, nullptr, Hdim,
      h2, nullptr, Hdim, Hdim, nullptr, offsets, tlist);
  // output head: q, action softmax, selected action
  expert_out_kernel<<<dim3(Bsz), 256, 0, stream>>>(h2, awo, abo, order, offsets, out);
}